// Round 7
// baseline (527.205 us; speedup 1.0000x reference)
//
#include <hip/hip_runtime.h>
#include <cstdint>
#include <type_traits>

typedef __attribute__((ext_vector_type(8))) short short8;
typedef __attribute__((ext_vector_type(4))) float floatx4;

#define NB 2
#define NS 2048
#define ND 2048
#define NH 16
#define NHD 128

__device__ __forceinline__ float b2f(short s) {
  unsigned u = ((unsigned)(unsigned short)s) << 16;
  return __builtin_bit_cast(float, u);
}
__device__ __forceinline__ short f2b(float f) {
  unsigned u = __builtin_bit_cast(unsigned, f);
  unsigned r = (u + 0x7fffu + ((u >> 16) & 1u)) >> 16;
  return (short)(unsigned short)r;
}

// ---------------- fused cast: x|wq|wk|wv|wo -> contiguous bf16 ws [xb|wqkvb|wob] -------
__global__ void cast_all(const float* __restrict__ x, const float* __restrict__ wq,
                         const float* __restrict__ wk, const float* __restrict__ wv,
                         const float* __restrict__ wo, short* __restrict__ dst) {
  const int i = blockIdx.x * blockDim.x + threadIdx.x;  // short4 units, block-uniform ranges
  const float* src;
  int off;
  if (i < 2097152) { src = x;  off = i; }
  else if (i < 3145728) { src = wq; off = i - 2097152; }
  else if (i < 4194304) { src = wk; off = i - 3145728; }
  else if (i < 5242880) { src = wv; off = i - 4194304; }
  else { src = wo; off = i - 5242880; }
  float4 v = ((const float4*)src)[off];
  short4 o;
  o.x = f2b(v.x); o.y = f2b(v.y); o.z = f2b(v.z); o.w = f2b(v.w);
  ((short4*)dst)[i] = o;
}

// ---------------- async global->LDS, 16B/lane ----------------
__device__ __forceinline__ void gld_lds16(const void* g, void* l) {
  __builtin_amdgcn_global_load_lds((const __attribute__((address_space(1))) void*)g,
                                   (__attribute__((address_space(3))) void*)l,
                                   16, 0, 0);
}

// ---------------- fused QKV GEMM, BK=64, XOR-swizzled LDS (proven 128^2, 838 TF) --------
// C = x (4096x2048) * Wqkv^T (6144x2048). col-block: 0-15 Q head-major, 16-31 K head-major,
// 32-47 V token-major. LDS[r][c] holds global chunk c^(r&7) (16B chunks, 8/row).
// R2 lesson: 256^2 4-phase/2-buffer dbuf regressed (vmcnt(0) drain at 1.5-2.5-phase
// distance < HBM latency; XCD swizzle raised FETCH 106->176MB). A retry needs the true
// m201 half-tile ring + counted vmcnt(6).
__global__ __launch_bounds__(256) void qkv_gemm(const short* __restrict__ A,
                                                const short* __restrict__ Bt,
                                                short* __restrict__ Qh,
                                                short* __restrict__ Kh,
                                                short* __restrict__ vlin) {
  constexpr int K = 2048;
  __shared__ short As[128 * 64];
  __shared__ short Bs[128 * 64];
  const int m0 = blockIdx.y * 128, n0 = blockIdx.x * 128;
  const int which = n0 >> 11;
  const int nl0 = n0 & 2047;
  const int t = threadIdx.x;
  const int wave = t >> 6, lane = t & 63, l15 = lane & 15, quad = lane >> 4;
  const int wm = (wave >> 1) * 64, wn = (wave & 1) * 64;

  floatx4 acc[4][4] = {};

  const int srow = t >> 3;                  // 0..31
  const int scol = (t & 7) ^ (srow & 7);    // swizzled global chunk for this lane
  const short* Ag = A + (long)(m0 + srow) * K + scol * 8;
  const short* Bg = Bt + (long)(n0 + srow) * K + scol * 8;
  char* AsB = (char*)As;
  char* BsB = (char*)Bs;
  const int ldsOff = wave * 1024;  // 8 rows x 128 B per wave

  for (int kt = 0; kt < K; kt += 64) {
#pragma unroll
    for (int i = 0; i < 4; ++i) {
      gld_lds16(Ag + kt + (long)(32 * i) * K, AsB + ldsOff + i * 4096);
      gld_lds16(Bg + kt + (long)(32 * i) * K, BsB + ldsOff + i * 4096);
    }
    __syncthreads();

#pragma unroll
    for (int half = 0; half < 2; ++half) {
      short8 a[4], b[4];
#pragma unroll
      for (int mi = 0; mi < 4; ++mi) {
        const int rr = wm + mi * 16 + l15;
        a[mi] = *(const short8*)&As[rr * 64 + (((half << 2) | quad) ^ (rr & 7)) * 8];
      }
#pragma unroll
      for (int ni = 0; ni < 4; ++ni) {
        const int rr = wn + ni * 16 + l15;
        b[ni] = *(const short8*)&Bs[rr * 64 + (((half << 2) | quad) ^ (rr & 7)) * 8];
      }
#pragma unroll
      for (int mi = 0; mi < 4; ++mi)
#pragma unroll
        for (int ni = 0; ni < 4; ++ni)
          acc[mi][ni] = __builtin_amdgcn_mfma_f32_16x16x32_bf16(a[mi], b[ni], acc[mi][ni], 0, 0, 0);
    }
    __syncthreads();
  }

  short* headDst = (which == 0) ? Qh : Kh;
#pragma unroll
  for (int mi = 0; mi < 4; ++mi) {
#pragma unroll
    for (int ni = 0; ni < 4; ++ni) {
#pragma unroll
      for (int r = 0; r < 4; ++r) {
        const int row = m0 + wm + mi * 16 + quad * 4 + r;
        const int col = nl0 + wn + ni * 16 + l15;
        const short v = f2b(acc[mi][ni][r]);
        if (which == 2) {
          vlin[(long)row * 2048 + col] = v;
        } else {
          const int bb = row >> 11, s = row & 2047, h = col >> 7, hd = col & 127;
          headDst[(((long)(bb * 16 + h) * 2048) + s) * 128 + hd] = v;
        }
      }
    }
  }
}

// ---------------- output GEMM: fp32 out, token-major; BK=64 swizzled ----------------
__global__ __launch_bounds__(256) void gemm_out(const short* __restrict__ A,
                                                const short* __restrict__ Bt,
                                                float* __restrict__ Cout) {
  constexpr int K = 2048, N = 2048;
  __shared__ short As[128 * 64];
  __shared__ short Bs[128 * 64];
  const int m0 = blockIdx.y * 128, n0 = blockIdx.x * 128;
  const int t = threadIdx.x;
  const int wave = t >> 6, lane = t & 63, l15 = lane & 15, quad = lane >> 4;
  const int wm = (wave >> 1) * 64, wn = (wave & 1) * 64;

  floatx4 acc[4][4] = {};

  const int srow = t >> 3;
  const int scol = (t & 7) ^ (srow & 7);
  const short* Ag = A + (long)(m0 + srow) * K + scol * 8;
  const short* Bg = Bt + (long)(n0 + srow) * K + scol * 8;
  char* AsB = (char*)As;
  char* BsB = (char*)Bs;
  const int ldsOff = wave * 1024;

  for (int kt = 0; kt < K; kt += 64) {
#pragma unroll
    for (int i = 0; i < 4; ++i) {
      gld_lds16(Ag + kt + (long)(32 * i) * K, AsB + ldsOff + i * 4096);
      gld_lds16(Bg + kt + (long)(32 * i) * K, BsB + ldsOff + i * 4096);
    }
    __syncthreads();

#pragma unroll
    for (int half = 0; half < 2; ++half) {
      short8 a[4], b[4];
#pragma unroll
      for (int mi = 0; mi < 4; ++mi) {
        const int rr = wm + mi * 16 + l15;
        a[mi] = *(const short8*)&As[rr * 64 + (((half << 2) | quad) ^ (rr & 7)) * 8];
      }
#pragma unroll
      for (int ni = 0; ni < 4; ++ni) {
        const int rr = wn + ni * 16 + l15;
        b[ni] = *(const short8*)&Bs[rr * 64 + (((half << 2) | quad) ^ (rr & 7)) * 8];
      }
#pragma unroll
      for (int mi = 0; mi < 4; ++mi)
#pragma unroll
        for (int ni = 0; ni < 4; ++ni)
          acc[mi][ni] = __builtin_amdgcn_mfma_f32_16x16x32_bf16(a[mi], b[ni], acc[mi][ni], 0, 0, 0);
    }
    __syncthreads();
  }

#pragma unroll
  for (int mi = 0; mi < 4; ++mi)
#pragma unroll
    for (int ni = 0; ni < 4; ++ni)
#pragma unroll
      for (int r = 0; r < 4; ++r) {
        const int row = m0 + wm + mi * 16 + quad * 4 + r;
        const int col = n0 + wn + ni * 16 + l15;
        Cout[(long)row * N + col] = acc[mi][ni][r];
      }
}

// ------------- merged RoPE (blocks 0..4095) + V transpose (blocks 4096..6143) -------------
__global__ __launch_bounds__(256) void rope_vtrans(short* __restrict__ Qh,
                                                   short* __restrict__ Kh,
                                                   const float* __restrict__ pos,
                                                   const short* __restrict__ v_lin,
                                                   short* __restrict__ Vt) {
  __shared__ short tile[64 * 72];
  const int bx = blockIdx.x;
  if (bx < 4096) {
    // ---- RoPE in-place on head-major Q,K: 4096 blocks x 256 = token(4096) x h(16) x kk(16)
    const int tid = bx * 256 + threadIdx.x;
    const int kk = tid & 15;
    const int h = (tid >> 4) & 15;
    const int token = tid >> 8;
    const int bb = token >> 11, s = token & 2047;
    const float4 p4 = ((const float4*)pos)[token];
    const float pv[4] = {p4.x, p4.y, p4.z, p4.w};
    const float theta = exp2f(-(float)kk * 0.8304820237218406f);
    const long base = (((long)(bb * 16 + h)) * 2048 + s) * 128 + kk * 8;
    short8 q8 = *(short8*)(Qh + base);
    short8 k8 = *(short8*)(Kh + base);
    short8 qo, ko;
#pragma unroll
    for (int jj = 0; jj < 4; ++jj) {
      const float fr = pv[jj] * theta;
      float sn, c;
      __sincosf(fr, &sn, &c);
      {
        const float tr = b2f(q8[2 * jj]), ti = b2f(q8[2 * jj + 1]);
        qo[2 * jj] = f2b(tr * c - ti * sn);
        qo[2 * jj + 1] = f2b(tr * sn + ti * c);
      }
      {
        const float tr = b2f(k8[2 * jj]), ti = b2f(k8[2 * jj + 1]);
        ko[2 * jj] = f2b(tr * c - ti * sn);
        ko[2 * jj + 1] = f2b(tr * sn + ti * c);
      }
    }
    *(short8*)(Qh + base) = qo;
    *(short8*)(Kh + base) = ko;
  } else {
    // ---- V transpose: vlin [token][h*128+hd] -> Vt [b][h][hd][s] ----
    const int b2 = bx - 4096;  // 0..2047
    const int s0 = (b2 & 31) * 64;
    const int hd0 = ((b2 >> 5) & 1) * 64;
    const int bh = b2 >> 6;
    const int bb = bh >> 4, h = bh & 15;
    const int t = threadIdx.x;
#pragma unroll
    for (int i = 0; i < 2; ++i) {
      const int ch = t + i * 256;
      const int r = ch >> 3, c = ch & 7;
      *(short8*)&tile[r * 72 + c * 8] =
          *(const short8*)(v_lin + (long)(bb * 2048 + s0 + r) * 2048 + h * 128 + hd0 + c * 8);
    }
    __syncthreads();
#pragma unroll
    for (int i = 0; i < 2; ++i) {
      const int ch = t + i * 256;
      const int r2 = ch >> 3, c2 = ch & 7;
      short8 o;
#pragma unroll
      for (int u = 0; u < 8; ++u) o[u] = tile[(c2 * 8 + u) * 72 + r2];
      *(short8*)(Vt + ((long)(bh * 128 + hd0 + r2)) * 2048 + s0 + c2 * 8) = o;
    }
  }
}

// ---------------- flash attention v6: in-block split-K, LPT dispatch ----------------
// R6 lessons: (1) mirror map put heavy blocks LAST -> serial tail, occ 3.3%, 208us.
//   LPT (heaviest first) is the only safe order for imbalanced blocks.
// (2) makespan == longest chain x solo step time (~5.2us); LPT alone only recovers ~167us.
// R7: halve the chain. 512 threads = 2 groups x 4 waves; group g does k-tiles g,g+2,...
// of the SAME 64-row q-tile. The no-max softmax makes split-K exactly additive:
// out = (accA+accB)/(lA+lB), no rescale. Heavy chain 32 -> 16 double-steps.
// LDS: 2x(Ks 16K + Vts 16K) + 8x Ps 2K = 80KB -> 2 blocks/CU, 16 waves/CU.
// Epilogue: grp1 dumps acc/l to LDS scratch (aliases Ks/Vts after post-loop barrier),
// grp0 combines and writes. VGPR ~86 < 128 cap of (512,4) -> no spill (watch WRITE_SIZE).
__global__ __launch_bounds__(512, 4) void flash(const short* __restrict__ Qh,
                                                const short* __restrict__ Kh,
                                                const short* __restrict__ Vt,
                                                short* __restrict__ ao) {
  __shared__ __align__(16) char smem[81920];
  short* KsB  = (short*)smem;              // [2][64*128]  32 KB
  short* VtsB = (short*)(smem + 32768);    // [2][128*64]  32 KB
  short* PsB  = (short*)(smem + 65536);    // [8][1024]    16 KB
  float* accS = (float*)smem;              // epilogue scratch [32][4][64] f32 (32 KB)
  float* lS   = (float*)(smem + 32768);    // epilogue scratch [4][4][64] f32 (4 KB)

  const int id = blockIdx.x;               // 0..1023
  const int qt = 31 - (id >> 5);           // LPT: qt=31 blocks are ids 0..31
  const int bh = id & 31;
  const int t = threadIdx.x;
  const int wave = t >> 6, lane = t & 63, l15 = lane & 15, quad = lane >> 4;
  const int grp = wave >> 2, wv = wave & 3;
  const int tg = t & 255;                  // thread index within group
  short* Ks  = KsB + grp * (64 * 128);
  short* Vts = VtsB + grp * (128 * 64);
  short* Ps  = PsB + wave * 1024;
  const int sqb = qt * 64;
  const int lastkt = qt;

  const short* Qbase = Qh + (long)bh * 2048 * 128;
  short8 aq[4];
#pragma unroll
  for (int ks = 0; ks < 4; ++ks)
    aq[ks] = *(const short8*)(Qbase + (long)(sqb + wv * 16 + l15) * 128 + ks * 32 + quad * 8);

  const short* KgBase = Kh + (long)bh * 2048 * 128;
  const short* VgBase = Vt + (long)bh * 128 * 2048;

  short8 kreg[4] = {}, vreg[4] = {};
  if (grp <= lastkt) {
#pragma unroll
    for (int i = 0; i < 4; ++i) {
      const int ch = tg + i * 256;
      kreg[i] = *(const short8*)(KgBase + (long)(grp * 64 + (ch >> 4)) * 128 + (ch & 15) * 8);
      vreg[i] = *(const short8*)(VgBase + (long)(ch >> 3) * 2048 + grp * 64 + (ch & 7) * 8);
    }
  }

  float l_part[4] = {};
  floatx4 acc_o[8] = {};
  const float CEXP = 0.12751745f;  // (1/sqrt(128)) * log2(e)

  for (int kt2 = 0; kt2 <= lastkt; kt2 += 2) {
    const int my_kt = kt2 + grp;
    const bool active = my_kt <= lastkt;
    const int k0 = my_kt * 64;
    if (kt2 > 0) __syncthreads();

    // ---- stage this group's tile into its swizzled LDS half ----
#pragma unroll
    for (int i = 0; i < 4; ++i) {
      const int ch = tg + i * 256;
      const int kr = ch >> 4, kc = ch & 15;
      *(short8*)&Ks[kr * 128 + (((kc & 7) ^ (kr & 7)) | (kc & 8)) * 8] = kreg[i];
      const int vr = ch >> 3, vc = ch & 7;
      *(short8*)&Vts[vr * 64 + (vc ^ (vr & 7)) * 8] = vreg[i];
    }
    __syncthreads();

    // ---- prefetch this group's tile after next (my_kt+2) ----
    if (my_kt + 2 <= lastkt) {
      const short* Kg = KgBase + (long)(my_kt + 2) * 64 * 128;
      const short* Vg = VgBase + (my_kt + 2) * 64;
#pragma unroll
      for (int i = 0; i < 4; ++i) {
        const int ch = tg + i * 256;
        kreg[i] = *(const short8*)(Kg + (long)(ch >> 4) * 128 + (ch & 15) * 8);
        vreg[i] = *(const short8*)(Vg + (long)(ch >> 3) * 2048 + (ch & 7) * 8);
      }
    }

    if (active) {
      const bool dg = (my_kt == lastkt);
      floatx4 accs[4] = {};
      __builtin_amdgcn_s_setprio(1);
#pragma unroll
      for (int ks = 0; ks < 4; ++ks) {
#pragma unroll
        for (int ni = 0; ni < 4; ++ni) {
          const int rr = ni * 16 + l15;
          const int c = ks * 4 + quad;  // logical chunk 0..15
          const short8 bk = *(const short8*)&Ks[rr * 128 + (((c & 7) ^ (rr & 7)) | (c & 8)) * 8];
          accs[ni] = __builtin_amdgcn_mfma_f32_16x16x32_bf16(aq[ks], bk, accs[ni], 0, 0, 0);
        }
      }
      __builtin_amdgcn_s_setprio(0);
#pragma unroll
      for (int r = 0; r < 4; ++r) {
        const int qrow = sqb + wv * 16 + quad * 4 + r;
        const int prow = quad * 4 + r;
#pragma unroll
        for (int ni = 0; ni < 4; ++ni) {
          float e = exp2f(accs[ni][r] * CEXP);
          if (dg && (k0 + ni * 16 + l15) > qrow) e = 0.f;
          const int pc = ni * 2 + (l15 >> 3);  // logical chunk 0..7
          Ps[prow * 64 + (pc ^ (prow & 7)) * 8 + (l15 & 7)] = f2b(e);
          l_part[r] += e;
        }
      }
      __builtin_amdgcn_s_setprio(1);
#pragma unroll
      for (int ks2 = 0; ks2 < 2; ++ks2) {
        const int pc = ks2 * 4 + quad;  // logical chunk 0..7
        const short8 ap = *(const short8*)&Ps[l15 * 64 + (pc ^ (l15 & 7)) * 8];
#pragma unroll
        for (int nh = 0; nh < 8; ++nh) {
          const int vr = nh * 16 + l15;
          const short8 bv = *(const short8*)&Vts[vr * 64 + (pc ^ (vr & 7)) * 8];
          acc_o[nh] = __builtin_amdgcn_mfma_f32_16x16x32_bf16(ap, bv, acc_o[nh], 0, 0, 0);
        }
      }
      __builtin_amdgcn_s_setprio(0);
    }
  }

  // ---- combine the two k-groups (exact: softmax is raw-sum form) ----
  __syncthreads();
  if (grp == 1) {
#pragma unroll
    for (int nh = 0; nh < 8; ++nh)
#pragma unroll
      for (int r = 0; r < 4; ++r)
        accS[((nh * 4 + r) * 4 + wv) * 64 + lane] = acc_o[nh][r];
#pragma unroll
    for (int r = 0; r < 4; ++r) lS[(r * 4 + wv) * 64 + lane] = l_part[r];
  }
  __syncthreads();
  if (grp == 0) {
#pragma unroll
    for (int nh = 0; nh < 8; ++nh)
#pragma unroll
      for (int r = 0; r < 4; ++r)
        acc_o[nh][r] += accS[((nh * 4 + r) * 4 + wv) * 64 + lane];
#pragma unroll
    for (int r = 0; r < 4; ++r) l_part[r] += lS[(r * 4 + wv) * 64 + lane];

    const int bb = bh >> 4, h = bh & 15;
#pragma unroll
    for (int r = 0; r < 4; ++r) {
      float rs = l_part[r];
#pragma unroll
      for (int mm = 8; mm >= 1; mm >>= 1) rs += __shfl_xor(rs, mm, 16);
      const float inv = 1.0f / rs;
      const int s = sqb + wv * 16 + quad * 4 + r;
      const long rowbase = ((long)(bb * 2048 + s)) * 2048 + h * 128;
#pragma unroll
      for (int nh = 0; nh < 8; ++nh) ao[rowbase + nh * 16 + l15] = f2b(acc_o[nh][r] * inv);
    }
  }
}

extern "C" void kernel_launch(void* const* d_in, const int* in_sizes, int n_in,
                              void* d_out, int out_size, void* d_ws, size_t ws_size,
                              hipStream_t stream) {
  const float* x = (const float*)d_in[0];
  const float* pos = (const float*)d_in[1];
  const float* wq = (const float*)d_in[3];
  const float* wk = (const float*)d_in[4];
  const float* wv = (const float*)d_in[5];
  const float* wo = (const float*)d_in[6];
  float* out = (float*)d_out;

  char* ws = (char*)d_ws;
  const size_t MB = 1024 * 1024;
  short* xb    = (short*)(ws + 0);        // 16 MB
  short* wqkvb = (short*)(ws + 16 * MB);  // 24 MB
  short* wob   = (short*)(ws + 40 * MB);  // 8 MB
  short* Qh    = (short*)(ws + 48 * MB);  // 16 MB
  short* Kh    = (short*)(ws + 64 * MB);  // 16 MB
  short* Vt    = (short*)(ws + 80 * MB);  // 16 MB
  short* vlin  = (short*)(ws + 96 * MB);  // 16 MB
  short* ao    = (short*)(ws + 96 * MB);  // alias vlin (vtrans consumes vlin before flash)
  // total 112 MB

  cast_all<<<24576, 256, 0, stream>>>(x, wq, wk, wv, wo, xb);

  qkv_gemm<<<dim3(48, 32), 256, 0, stream>>>(xb, wqkvb, Qh, Kh, vlin);

  rope_vtrans<<<6144, 256, 0, stream>>>(Qh, Kh, pos, vlin, Vt);

  flash<<<1024, 512, 0, stream>>>(Qh, Kh, Vt, ao);

  gemm_out<<<dim3(16, 32), 256, 0, stream>>>(ao, wob, out);
}

// Round 8
// 391.866 us; speedup vs baseline: 1.3454x; 1.3454x over previous
//
#include <hip/hip_runtime.h>
#include <cstdint>
#include <type_traits>

typedef __attribute__((ext_vector_type(8))) short short8;
typedef __attribute__((ext_vector_type(4))) float floatx4;

#define NB 2
#define NS 2048
#define ND 2048
#define NH 16
#define NHD 128

__device__ __forceinline__ float b2f(short s) {
  unsigned u = ((unsigned)(unsigned short)s) << 16;
  return __builtin_bit_cast(float, u);
}
__device__ __forceinline__ short f2b(float f) {
  unsigned u = __builtin_bit_cast(unsigned, f);
  unsigned r = (u + 0x7fffu + ((u >> 16) & 1u)) >> 16;
  return (short)(unsigned short)r;
}

// ---------------- fused cast: x|wq|wk|wv|wo -> contiguous bf16 ws [xb|wqkvb|wob] -------
__global__ void cast_all(const float* __restrict__ x, const float* __restrict__ wq,
                         const float* __restrict__ wk, const float* __restrict__ wv,
                         const float* __restrict__ wo, short* __restrict__ dst) {
  const int i = blockIdx.x * blockDim.x + threadIdx.x;  // short4 units, block-uniform ranges
  const float* src;
  int off;
  if (i < 2097152) { src = x;  off = i; }
  else if (i < 3145728) { src = wq; off = i - 2097152; }
  else if (i < 4194304) { src = wk; off = i - 3145728; }
  else if (i < 5242880) { src = wv; off = i - 4194304; }
  else { src = wo; off = i - 5242880; }
  float4 v = ((const float4*)src)[off];
  short4 o;
  o.x = f2b(v.x); o.y = f2b(v.y); o.z = f2b(v.z); o.w = f2b(v.w);
  ((short4*)dst)[i] = o;
}

// ---------------- async global->LDS, 16B/lane ----------------
__device__ __forceinline__ void gld_lds16(const void* g, void* l) {
  __builtin_amdgcn_global_load_lds((const __attribute__((address_space(1))) void*)g,
                                   (__attribute__((address_space(3))) void*)l,
                                   16, 0, 0);
}

// ---------------- fused QKV GEMM, BK=64, XOR-swizzled LDS (proven 128^2, 838 TF) --------
// C = x (4096x2048) * Wqkv^T (6144x2048). col-block: 0-15 Q head-major, 16-31 K head-major,
// 32-47 V token-major. LDS[r][c] holds global chunk c^(r&7) (16B chunks, 8/row).
__global__ __launch_bounds__(256) void qkv_gemm(const short* __restrict__ A,
                                                const short* __restrict__ Bt,
                                                short* __restrict__ Qh,
                                                short* __restrict__ Kh,
                                                short* __restrict__ vlin) {
  constexpr int K = 2048;
  __shared__ short As[128 * 64];
  __shared__ short Bs[128 * 64];
  const int m0 = blockIdx.y * 128, n0 = blockIdx.x * 128;
  const int which = n0 >> 11;
  const int nl0 = n0 & 2047;
  const int t = threadIdx.x;
  const int wave = t >> 6, lane = t & 63, l15 = lane & 15, quad = lane >> 4;
  const int wm = (wave >> 1) * 64, wn = (wave & 1) * 64;

  floatx4 acc[4][4] = {};

  const int srow = t >> 3;                  // 0..31
  const int scol = (t & 7) ^ (srow & 7);    // swizzled global chunk for this lane
  const short* Ag = A + (long)(m0 + srow) * K + scol * 8;
  const short* Bg = Bt + (long)(n0 + srow) * K + scol * 8;
  char* AsB = (char*)As;
  char* BsB = (char*)Bs;
  const int ldsOff = wave * 1024;  // 8 rows x 128 B per wave

  for (int kt = 0; kt < K; kt += 64) {
#pragma unroll
    for (int i = 0; i < 4; ++i) {
      gld_lds16(Ag + kt + (long)(32 * i) * K, AsB + ldsOff + i * 4096);
      gld_lds16(Bg + kt + (long)(32 * i) * K, BsB + ldsOff + i * 4096);
    }
    __syncthreads();

#pragma unroll
    for (int half = 0; half < 2; ++half) {
      short8 a[4], b[4];
#pragma unroll
      for (int mi = 0; mi < 4; ++mi) {
        const int rr = wm + mi * 16 + l15;
        a[mi] = *(const short8*)&As[rr * 64 + (((half << 2) | quad) ^ (rr & 7)) * 8];
      }
#pragma unroll
      for (int ni = 0; ni < 4; ++ni) {
        const int rr = wn + ni * 16 + l15;
        b[ni] = *(const short8*)&Bs[rr * 64 + (((half << 2) | quad) ^ (rr & 7)) * 8];
      }
#pragma unroll
      for (int mi = 0; mi < 4; ++mi)
#pragma unroll
        for (int ni = 0; ni < 4; ++ni)
          acc[mi][ni] = __builtin_amdgcn_mfma_f32_16x16x32_bf16(a[mi], b[ni], acc[mi][ni], 0, 0, 0);
    }
    __syncthreads();
  }

  short* headDst = (which == 0) ? Qh : Kh;
#pragma unroll
  for (int mi = 0; mi < 4; ++mi) {
#pragma unroll
    for (int ni = 0; ni < 4; ++ni) {
#pragma unroll
      for (int r = 0; r < 4; ++r) {
        const int row = m0 + wm + mi * 16 + quad * 4 + r;
        const int col = nl0 + wn + ni * 16 + l15;
        const short v = f2b(acc[mi][ni][r]);
        if (which == 2) {
          vlin[(long)row * 2048 + col] = v;
        } else {
          const int bb = row >> 11, s = row & 2047, h = col >> 7, hd = col & 127;
          headDst[(((long)(bb * 16 + h) * 2048) + s) * 128 + hd] = v;
        }
      }
    }
  }
}

// ---------------- output GEMM: fp32 out, token-major; BK=64 swizzled ----------------
__global__ __launch_bounds__(256) void gemm_out(const short* __restrict__ A,
                                                const short* __restrict__ Bt,
                                                float* __restrict__ Cout) {
  constexpr int K = 2048, N = 2048;
  __shared__ short As[128 * 64];
  __shared__ short Bs[128 * 64];
  const int m0 = blockIdx.y * 128, n0 = blockIdx.x * 128;
  const int t = threadIdx.x;
  const int wave = t >> 6, lane = t & 63, l15 = lane & 15, quad = lane >> 4;
  const int wm = (wave >> 1) * 64, wn = (wave & 1) * 64;

  floatx4 acc[4][4] = {};

  const int srow = t >> 3;
  const int scol = (t & 7) ^ (srow & 7);
  const short* Ag = A + (long)(m0 + srow) * K + scol * 8;
  const short* Bg = Bt + (long)(n0 + srow) * K + scol * 8;
  char* AsB = (char*)As;
  char* BsB = (char*)Bs;
  const int ldsOff = wave * 1024;

  for (int kt = 0; kt < K; kt += 64) {
#pragma unroll
    for (int i = 0; i < 4; ++i) {
      gld_lds16(Ag + kt + (long)(32 * i) * K, AsB + ldsOff + i * 4096);
      gld_lds16(Bg + kt + (long)(32 * i) * K, BsB + ldsOff + i * 4096);
    }
    __syncthreads();

#pragma unroll
    for (int half = 0; half < 2; ++half) {
      short8 a[4], b[4];
#pragma unroll
      for (int mi = 0; mi < 4; ++mi) {
        const int rr = wm + mi * 16 + l15;
        a[mi] = *(const short8*)&As[rr * 64 + (((half << 2) | quad) ^ (rr & 7)) * 8];
      }
#pragma unroll
      for (int ni = 0; ni < 4; ++ni) {
        const int rr = wn + ni * 16 + l15;
        b[ni] = *(const short8*)&Bs[rr * 64 + (((half << 2) | quad) ^ (rr & 7)) * 8];
      }
#pragma unroll
      for (int mi = 0; mi < 4; ++mi)
#pragma unroll
        for (int ni = 0; ni < 4; ++ni)
          acc[mi][ni] = __builtin_amdgcn_mfma_f32_16x16x32_bf16(a[mi], b[ni], acc[mi][ni], 0, 0, 0);
    }
    __syncthreads();
  }

#pragma unroll
  for (int mi = 0; mi < 4; ++mi)
#pragma unroll
    for (int ni = 0; ni < 4; ++ni)
#pragma unroll
      for (int r = 0; r < 4; ++r) {
        const int row = m0 + wm + mi * 16 + quad * 4 + r;
        const int col = n0 + wn + ni * 16 + l15;
        Cout[(long)row * N + col] = acc[mi][ni][r];
      }
}

// ------------- merged RoPE (blocks 0..4095) + V transpose (blocks 4096..6143) -------------
__global__ __launch_bounds__(256) void rope_vtrans(short* __restrict__ Qh,
                                                   short* __restrict__ Kh,
                                                   const float* __restrict__ pos,
                                                   const short* __restrict__ v_lin,
                                                   short* __restrict__ Vt) {
  __shared__ short tile[64 * 72];
  const int bx = blockIdx.x;
  if (bx < 4096) {
    // ---- RoPE in-place on head-major Q,K: 4096 blocks x 256 = token(4096) x h(16) x kk(16)
    const int tid = bx * 256 + threadIdx.x;
    const int kk = tid & 15;
    const int h = (tid >> 4) & 15;
    const int token = tid >> 8;
    const int bb = token >> 11, s = token & 2047;
    const float4 p4 = ((const float4*)pos)[token];
    const float pv[4] = {p4.x, p4.y, p4.z, p4.w};
    const float theta = exp2f(-(float)kk * 0.8304820237218406f);
    const long base = (((long)(bb * 16 + h)) * 2048 + s) * 128 + kk * 8;
    short8 q8 = *(short8*)(Qh + base);
    short8 k8 = *(short8*)(Kh + base);
    short8 qo, ko;
#pragma unroll
    for (int jj = 0; jj < 4; ++jj) {
      const float fr = pv[jj] * theta;
      float sn, c;
      __sincosf(fr, &sn, &c);
      {
        const float tr = b2f(q8[2 * jj]), ti = b2f(q8[2 * jj + 1]);
        qo[2 * jj] = f2b(tr * c - ti * sn);
        qo[2 * jj + 1] = f2b(tr * sn + ti * c);
      }
      {
        const float tr = b2f(k8[2 * jj]), ti = b2f(k8[2 * jj + 1]);
        ko[2 * jj] = f2b(tr * c - ti * sn);
        ko[2 * jj + 1] = f2b(tr * sn + ti * c);
      }
    }
    *(short8*)(Qh + base) = qo;
    *(short8*)(Kh + base) = ko;
  } else {
    // ---- V transpose: vlin [token][h*128+hd] -> Vt [b][h][hd][s] ----
    const int b2 = bx - 4096;  // 0..2047
    const int s0 = (b2 & 31) * 64;
    const int hd0 = ((b2 >> 5) & 1) * 64;
    const int bh = b2 >> 6;
    const int bb = bh >> 4, h = bh & 15;
    const int t = threadIdx.x;
#pragma unroll
    for (int i = 0; i < 2; ++i) {
      const int ch = t + i * 256;
      const int r = ch >> 3, c = ch & 7;
      *(short8*)&tile[r * 72 + c * 8] =
          *(const short8*)(v_lin + (long)(bb * 2048 + s0 + r) * 2048 + h * 128 + hd0 + c * 8);
    }
    __syncthreads();
#pragma unroll
    for (int i = 0; i < 2; ++i) {
      const int ch = t + i * 256;
      const int r2 = ch >> 3, c2 = ch & 7;
      short8 o;
#pragma unroll
      for (int u = 0; u < 8; ++u) o[u] = tile[(c2 * 8 + u) * 72 + r2];
      *(short8*)(Vt + ((long)(bh * 128 + hd0 + r2)) * 2048 + s0 + c2 * 8) = o;
    }
  }
}

// ---------------- flash attention v7: R6 proven body + LPT dispatch ----------------
// R7 lesson: __launch_bounds__ 2nd arg >= 4 caps total regs at 512/arg -> this body
// (~84 arch + ~48 acc = ~132) spills. Flash-family: arg <= 3 ONLY. 512-thread split-K
// is register-boxed (needs 132 > 128 for 2 blocks/CU) -> shelved.
// R6 lesson: heavy-last dispatch -> serial tail (66 steps x 3.15us solo = 208us exact).
// R7 fix: LPT (heaviest-first) bijective map: ids 0..31 are the 32-step blocks.
// Expected capacity-bound: 66 steps/CU / 3 slots at ~2.5us concurrent step => ~160-172us.
__global__ __launch_bounds__(256, 3) void flash(const short* __restrict__ Qh,
                                                const short* __restrict__ Kh,
                                                const short* __restrict__ Vt,
                                                short* __restrict__ ao) {
  __shared__ short Ks[64 * 128];    // 16384 B: row=k (64), 16 chunks of 8sh; phys chunk = (c&8)|((c&7)^(row&7))
  __shared__ short Vts[128 * 64];   // 16384 B: row=hd (128), 8 chunks; phys chunk = c^(row&7)
  __shared__ short Ps[4 * 16 * 64]; // 8192 B: per-wave [16][64], 8 chunks; phys chunk = c^(row&7)
  const int id = blockIdx.x;        // 0..1023
  const int qt = 31 - (id >> 5);    // LPT: heaviest (qt=31) first
  const int bh = id & 31;
  const int t = threadIdx.x, wave = t >> 6, lane = t & 63, l15 = lane & 15, quad = lane >> 4;
  const int sqb = qt * 64;
  const int lastkt = qt;

  const short* Qbase = Qh + (long)bh * 2048 * 128;
  short8 aq[4];
#pragma unroll
  for (int ks = 0; ks < 4; ++ks)
    aq[ks] = *(const short8*)(Qbase + (long)(sqb + wave * 16 + l15) * 128 + ks * 32 + quad * 8);

  const short* KgBase = Kh + (long)bh * 2048 * 128;
  const short* VgBase = Vt + (long)bh * 128 * 2048;

  short8 kreg[4], vreg[4];
#pragma unroll
  for (int i = 0; i < 4; ++i) {
    const int ch = t + i * 256;
    kreg[i] = *(const short8*)(KgBase + (long)(ch >> 4) * 128 + (ch & 15) * 8);
    vreg[i] = *(const short8*)(VgBase + (long)(ch >> 3) * 2048 + (ch & 7) * 8);
  }

  float l_part[4] = {};
  floatx4 acc_o[8] = {};
  const float CEXP = 0.12751745f;  // (1/sqrt(128)) * log2(e)

  for (int kt = 0; kt <= lastkt; ++kt) {
    const int k0 = kt * 64;
    if (kt > 0) __syncthreads();

    // ---- stage K/V tile kt into swizzled LDS ----
#pragma unroll
    for (int i = 0; i < 4; ++i) {
      const int ch = t + i * 256;
      const int kr = ch >> 4, kc = ch & 15;
      *(short8*)&Ks[kr * 128 + (((kc & 7) ^ (kr & 7)) | (kc & 8)) * 8] = kreg[i];
      const int vr = ch >> 3, vc = ch & 7;
      *(short8*)&Vts[vr * 64 + (vc ^ (vr & 7)) * 8] = vreg[i];
    }
    __syncthreads();

    if (kt < lastkt) {
      const short* Kg = KgBase + (long)(k0 + 64) * 128;
      const short* Vg = VgBase + (k0 + 64);
#pragma unroll
      for (int i = 0; i < 4; ++i) {
        const int ch = t + i * 256;
        kreg[i] = *(const short8*)(Kg + (long)(ch >> 4) * 128 + (ch & 15) * 8);
        vreg[i] = *(const short8*)(Vg + (long)(ch >> 3) * 2048 + (ch & 7) * 8);
      }
    }

    const bool dg = (kt == lastkt);
    floatx4 accs[4] = {};
    __builtin_amdgcn_s_setprio(1);
#pragma unroll
    for (int ks = 0; ks < 4; ++ks) {
#pragma unroll
      for (int ni = 0; ni < 4; ++ni) {
        const int rr = ni * 16 + l15;
        const int c = ks * 4 + quad;  // logical chunk 0..15
        const short8 bk = *(const short8*)&Ks[rr * 128 + (((c & 7) ^ (rr & 7)) | (c & 8)) * 8];
        accs[ni] = __builtin_amdgcn_mfma_f32_16x16x32_bf16(aq[ks], bk, accs[ni], 0, 0, 0);
      }
    }
    __builtin_amdgcn_s_setprio(0);
#pragma unroll
    for (int r = 0; r < 4; ++r) {
      const int qrow = sqb + wave * 16 + quad * 4 + r;
      const int prow = quad * 4 + r;
#pragma unroll
      for (int ni = 0; ni < 4; ++ni) {
        float e = exp2f(accs[ni][r] * CEXP);
        if (dg && (k0 + ni * 16 + l15) > qrow) e = 0.f;
        const int pc = ni * 2 + (l15 >> 3);  // logical chunk 0..7
        Ps[wave * 1024 + prow * 64 + (pc ^ (prow & 7)) * 8 + (l15 & 7)] = f2b(e);
        l_part[r] += e;
      }
    }
    __builtin_amdgcn_s_setprio(1);
#pragma unroll
    for (int ks2 = 0; ks2 < 2; ++ks2) {
      const int pc = ks2 * 4 + quad;  // logical chunk 0..7
      const short8 ap = *(const short8*)&Ps[wave * 1024 + l15 * 64 + (pc ^ (l15 & 7)) * 8];
#pragma unroll
      for (int nh = 0; nh < 8; ++nh) {
        const int vr = nh * 16 + l15;
        const short8 bv = *(const short8*)&Vts[vr * 64 + (pc ^ (vr & 7)) * 8];
        acc_o[nh] = __builtin_amdgcn_mfma_f32_16x16x32_bf16(ap, bv, acc_o[nh], 0, 0, 0);
      }
    }
    __builtin_amdgcn_s_setprio(0);
  }

  const int bb = bh >> 4, h = bh & 15;
#pragma unroll
  for (int r = 0; r < 4; ++r) {
    float rs = l_part[r];
#pragma unroll
    for (int mm = 8; mm >= 1; mm >>= 1) rs += __shfl_xor(rs, mm, 16);
    const float inv = 1.0f / rs;
    const int s = sqb + wave * 16 + quad * 4 + r;
    const long rowbase = ((long)(bb * 2048 + s)) * 2048 + h * 128;
#pragma unroll
    for (int nh = 0; nh < 8; ++nh) ao[rowbase + nh * 16 + l15] = f2b(acc_o[nh][r] * inv);
  }
}

extern "C" void kernel_launch(void* const* d_in, const int* in_sizes, int n_in,
                              void* d_out, int out_size, void* d_ws, size_t ws_size,
                              hipStream_t stream) {
  const float* x = (const float*)d_in[0];
  const float* pos = (const float*)d_in[1];
  const float* wq = (const float*)d_in[3];
  const float* wk = (const float*)d_in[4];
  const float* wv = (const float*)d_in[5];
  const float* wo = (const float*)d_in[6];
  float* out = (float*)d_out;

  char* ws = (char*)d_ws;
  const size_t MB = 1024 * 1024;
  short* xb    = (short*)(ws + 0);        // 16 MB
  short* wqkvb = (short*)(ws + 16 * MB);  // 24 MB
  short* wob   = (short*)(ws + 40 * MB);  // 8 MB
  short* Qh    = (short*)(ws + 48 * MB);  // 16 MB
  short* Kh    = (short*)(ws + 64 * MB);  // 16 MB
  short* Vt    = (short*)(ws + 80 * MB);  // 16 MB
  short* vlin  = (short*)(ws + 96 * MB);  // 16 MB
  short* ao    = (short*)(ws + 96 * MB);  // alias vlin (vtrans consumes vlin before flash)
  // total 112 MB

  cast_all<<<24576, 256, 0, stream>>>(x, wq, wk, wv, wo, xb);

  qkv_gemm<<<dim3(48, 32), 256, 0, stream>>>(xb, wqkvb, Qh, Kh, vlin);

  rope_vtrans<<<6144, 256, 0, stream>>>(Qh, Kh, pos, vlin, Vt);

  flash<<<1024, 256, 0, stream>>>(Qh, Kh, Vt, ao);

  gemm_out<<<dim3(16, 32), 256, 0, stream>>>(ao, wob, out);
}

// Round 9
// 389.748 us; speedup vs baseline: 1.3527x; 1.0054x over previous
//
#include <hip/hip_runtime.h>
#include <cstdint>
#include <type_traits>

typedef __attribute__((ext_vector_type(8))) short short8;
typedef __attribute__((ext_vector_type(4))) float floatx4;

#define NB 2
#define NS 2048
#define ND 2048
#define NH 16
#define NHD 128

__device__ __forceinline__ float b2f(short s) {
  unsigned u = ((unsigned)(unsigned short)s) << 16;
  return __builtin_bit_cast(float, u);
}
__device__ __forceinline__ short f2b(float f) {
  unsigned u = __builtin_bit_cast(unsigned, f);
  unsigned r = (u + 0x7fffu + ((u >> 16) & 1u)) >> 16;
  return (short)(unsigned short)r;
}

// ---------------- fused cast: x|wq|wk|wv|wo -> contiguous bf16 ws [xb|wqkvb|wob] -------
__global__ void cast_all(const float* __restrict__ x, const float* __restrict__ wq,
                         const float* __restrict__ wk, const float* __restrict__ wv,
                         const float* __restrict__ wo, short* __restrict__ dst) {
  const int i = blockIdx.x * blockDim.x + threadIdx.x;  // short4 units, block-uniform ranges
  const float* src;
  int off;
  if (i < 2097152) { src = x;  off = i; }
  else if (i < 3145728) { src = wq; off = i - 2097152; }
  else if (i < 4194304) { src = wk; off = i - 3145728; }
  else if (i < 5242880) { src = wv; off = i - 4194304; }
  else { src = wo; off = i - 5242880; }
  float4 v = ((const float4*)src)[off];
  short4 o;
  o.x = f2b(v.x); o.y = f2b(v.y); o.z = f2b(v.z); o.w = f2b(v.w);
  ((short4*)dst)[i] = o;
}

// ---------------- async global->LDS, 16B/lane ----------------
__device__ __forceinline__ void gld_lds16(const void* g, void* l) {
  __builtin_amdgcn_global_load_lds((const __attribute__((address_space(1))) void*)g,
                                   (__attribute__((address_space(3))) void*)l,
                                   16, 0, 0);
}

// ---------------- fused QKV GEMM v2: 256x128 tile, ring-3 LDS, counted vmcnt(6) --------
// R2 lesson applied: 2-buffer K-tile dbuf can't exceed ~1-phase issue->drain distance;
// the fix is a ring>=3. BM=256,BN=128,BK=64: ring-3 LDS = 3x(32K+16K)=144KB, 1 block/CU,
// grid 48x16=768 = 3 FULL dispatch rounds. 512 thr, 8 waves (4Mx2N), per-wave 64x64,
// 2 phases/K-tile {8 ds_read, 3 stage, barrier, 16 MFMA, barrier}. Stage T+2 during T;
// vmcnt(6) at T's phase1 leaves exactly T+2's 6 loads outstanding => T+1 landed, issued
// a full K-tile earlier. Raw s_barrier (NOT __syncthreads: compiler would insert its own
// vmcnt(0) drain and reproduce R2). Chunk-XOR swizzle unchanged (measured 0 conflicts).
// Race audit: stage(T+2) targets slot (T-1)%3, freed by the barrier preceding the stage;
// vmcnt-then-barrier extends per-wave load guarantees to all waves.
__global__ __launch_bounds__(512, 2) void qkv_gemm(const short* __restrict__ A,
                                                   const short* __restrict__ Bt,
                                                   short* __restrict__ Qh,
                                                   short* __restrict__ Kh,
                                                   short* __restrict__ vlin) {
  constexpr int K = 2048, NT = K / 64;  // 32 K-tiles
  __shared__ __align__(16) char lds[147456];  // A ring 3x32768 @0; B ring 3x16384 @98304
  const int m0 = blockIdx.y * 256, n0 = blockIdx.x * 128;
  const int which = n0 >> 11;
  const int nl0 = n0 & 2047;
  const int t = threadIdx.x;
  const int wave = t >> 6, lane = t & 63, l15 = lane & 15, quad = lane >> 4;
  const int wr = wave >> 1, wc = wave & 1;  // 4x2 wave grid, per-wave 64x64 output

  floatx4 acc[4][4] = {};

  const int srow = t >> 3;                  // 0..63
  const int scol = (t & 7) ^ (srow & 7);    // pre-swizzled global chunk
  const short* Ag = A + (long)(m0 + srow) * K + scol * 8;
  const short* Bg = Bt + (long)(n0 + srow) * K + scol * 8;
  const int wOff = wave * 1024;             // per-wave 64 lanes x 16B per issue

  // ---- prologue: stage tiles 0 (slot 0) and 1 (slot 1); vmcnt(6) -> tile 0 landed ----
#pragma unroll
  for (int i = 0; i < 4; ++i) gld_lds16(Ag + (long)(i * 64) * K, lds + 0 * 32768 + i * 8192 + wOff);
#pragma unroll
  for (int i = 0; i < 2; ++i) gld_lds16(Bg + (long)(i * 64) * K, lds + 98304 + 0 * 16384 + i * 8192 + wOff);
#pragma unroll
  for (int i = 0; i < 4; ++i) gld_lds16(Ag + 64 + (long)(i * 64) * K, lds + 1 * 32768 + i * 8192 + wOff);
#pragma unroll
  for (int i = 0; i < 2; ++i) gld_lds16(Bg + 64 + (long)(i * 64) * K, lds + 98304 + 1 * 16384 + i * 8192 + wOff);
  asm volatile("s_waitcnt vmcnt(6)" ::: "memory");
  __builtin_amdgcn_s_barrier();

  int scur = 0;
  for (int T = 0; T < NT; ++T) {
    const int snext = (scur >= 1) ? scur - 1 : scur + 2;  // (T+2)%3
    const short* At = (const short*)(lds + scur * 32768);
    const short* Btl = (const short*)(lds + 98304 + scur * 16384);
    char* An = lds + snext * 32768;
    char* Bn = lds + 98304 + snext * 16384;
    const long knext = (long)(T + 2) * 64;
    const bool more = (T + 2) < NT;

    // ======== phase 0: kk = 0 ========
    {
      short8 a[4], b[4];
#pragma unroll
      for (int mi = 0; mi < 4; ++mi) {
        const int rr = wr * 64 + mi * 16 + l15;
        a[mi] = *(const short8*)&At[rr * 64 + (quad ^ (rr & 7)) * 8];
      }
#pragma unroll
      for (int ni = 0; ni < 4; ++ni) {
        const int rr = wc * 64 + ni * 16 + l15;
        b[ni] = *(const short8*)&Btl[rr * 64 + (quad ^ (rr & 7)) * 8];
      }
      if (more) {
#pragma unroll
        for (int i = 0; i < 3; ++i) gld_lds16(Ag + knext + (long)(i * 64) * K, An + i * 8192 + wOff);
      }
      __builtin_amdgcn_s_barrier();
      __builtin_amdgcn_s_setprio(1);
#pragma unroll
      for (int mi = 0; mi < 4; ++mi)
#pragma unroll
        for (int ni = 0; ni < 4; ++ni)
          acc[mi][ni] = __builtin_amdgcn_mfma_f32_16x16x32_bf16(a[mi], b[ni], acc[mi][ni], 0, 0, 0);
      __builtin_amdgcn_s_setprio(0);
      __builtin_amdgcn_s_barrier();
    }

    // ======== phase 1: kk = 1 ========
    {
      short8 a[4], b[4];
#pragma unroll
      for (int mi = 0; mi < 4; ++mi) {
        const int rr = wr * 64 + mi * 16 + l15;
        a[mi] = *(const short8*)&At[rr * 64 + ((4 | quad) ^ (rr & 7)) * 8];
      }
#pragma unroll
      for (int ni = 0; ni < 4; ++ni) {
        const int rr = wc * 64 + ni * 16 + l15;
        b[ni] = *(const short8*)&Btl[rr * 64 + ((4 | quad) ^ (rr & 7)) * 8];
      }
      if (more) {
        gld_lds16(Ag + knext + (long)(3 * 64) * K, An + 3 * 8192 + wOff);
#pragma unroll
        for (int i = 0; i < 2; ++i) gld_lds16(Bg + knext + (long)(i * 64) * K, Bn + i * 8192 + wOff);
        asm volatile("s_waitcnt vmcnt(6)" ::: "memory");
      } else {
        asm volatile("s_waitcnt vmcnt(0)" ::: "memory");
      }
      __builtin_amdgcn_s_barrier();
      __builtin_amdgcn_s_setprio(1);
#pragma unroll
      for (int mi = 0; mi < 4; ++mi)
#pragma unroll
        for (int ni = 0; ni < 4; ++ni)
          acc[mi][ni] = __builtin_amdgcn_mfma_f32_16x16x32_bf16(a[mi], b[ni], acc[mi][ni], 0, 0, 0);
      __builtin_amdgcn_s_setprio(0);
      __builtin_amdgcn_s_barrier();
    }

    scur = (scur + 1 == 3) ? 0 : scur + 1;
  }

  short* headDst = (which == 0) ? Qh : Kh;
#pragma unroll
  for (int mi = 0; mi < 4; ++mi) {
#pragma unroll
    for (int ni = 0; ni < 4; ++ni) {
#pragma unroll
      for (int r = 0; r < 4; ++r) {
        const int row = m0 + wr * 64 + mi * 16 + quad * 4 + r;
        const int col = nl0 + wc * 64 + ni * 16 + l15;
        const short v = f2b(acc[mi][ni][r]);
        if (which == 2) {
          vlin[(long)row * 2048 + col] = v;
        } else {
          const int bb = row >> 11, s = row & 2047, h = col >> 7, hd = col & 127;
          headDst[(((long)(bb * 16 + h) * 2048) + s) * 128 + hd] = v;
        }
      }
    }
  }
}

// ---------------- output GEMM: fp32 out, token-major; BK=64 swizzled ----------------
__global__ __launch_bounds__(256) void gemm_out(const short* __restrict__ A,
                                                const short* __restrict__ Bt,
                                                float* __restrict__ Cout) {
  constexpr int K = 2048, N = 2048;
  __shared__ short As[128 * 64];
  __shared__ short Bs[128 * 64];
  const int m0 = blockIdx.y * 128, n0 = blockIdx.x * 128;
  const int t = threadIdx.x;
  const int wave = t >> 6, lane = t & 63, l15 = lane & 15, quad = lane >> 4;
  const int wm = (wave >> 1) * 64, wn = (wave & 1) * 64;

  floatx4 acc[4][4] = {};

  const int srow = t >> 3;
  const int scol = (t & 7) ^ (srow & 7);
  const short* Ag = A + (long)(m0 + srow) * K + scol * 8;
  const short* Bg = Bt + (long)(n0 + srow) * K + scol * 8;
  char* AsB = (char*)As;
  char* BsB = (char*)Bs;
  const int ldsOff = wave * 1024;

  for (int kt = 0; kt < K; kt += 64) {
#pragma unroll
    for (int i = 0; i < 4; ++i) {
      gld_lds16(Ag + kt + (long)(32 * i) * K, AsB + ldsOff + i * 4096);
      gld_lds16(Bg + kt + (long)(32 * i) * K, BsB + ldsOff + i * 4096);
    }
    __syncthreads();

#pragma unroll
    for (int half = 0; half < 2; ++half) {
      short8 a[4], b[4];
#pragma unroll
      for (int mi = 0; mi < 4; ++mi) {
        const int rr = wm + mi * 16 + l15;
        a[mi] = *(const short8*)&As[rr * 64 + (((half << 2) | quad) ^ (rr & 7)) * 8];
      }
#pragma unroll
      for (int ni = 0; ni < 4; ++ni) {
        const int rr = wn + ni * 16 + l15;
        b[ni] = *(const short8*)&Bs[rr * 64 + (((half << 2) | quad) ^ (rr & 7)) * 8];
      }
#pragma unroll
      for (int mi = 0; mi < 4; ++mi)
#pragma unroll
        for (int ni = 0; ni < 4; ++ni)
          acc[mi][ni] = __builtin_amdgcn_mfma_f32_16x16x32_bf16(a[mi], b[ni], acc[mi][ni], 0, 0, 0);
    }
    __syncthreads();
  }

#pragma unroll
  for (int mi = 0; mi < 4; ++mi)
#pragma unroll
    for (int ni = 0; ni < 4; ++ni)
#pragma unroll
      for (int r = 0; r < 4; ++r) {
        const int row = m0 + wm + mi * 16 + quad * 4 + r;
        const int col = n0 + wn + ni * 16 + l15;
        Cout[(long)row * N + col] = acc[mi][ni][r];
      }
}

// ------------- merged RoPE (blocks 0..4095) + V transpose (blocks 4096..6143) -------------
__global__ __launch_bounds__(256) void rope_vtrans(short* __restrict__ Qh,
                                                   short* __restrict__ Kh,
                                                   const float* __restrict__ pos,
                                                   const short* __restrict__ v_lin,
                                                   short* __restrict__ Vt) {
  __shared__ short tile[64 * 72];
  const int bx = blockIdx.x;
  if (bx < 4096) {
    // ---- RoPE in-place on head-major Q,K: 4096 blocks x 256 = token(4096) x h(16) x kk(16)
    const int tid = bx * 256 + threadIdx.x;
    const int kk = tid & 15;
    const int h = (tid >> 4) & 15;
    const int token = tid >> 8;
    const int bb = token >> 11, s = token & 2047;
    const float4 p4 = ((const float4*)pos)[token];
    const float pv[4] = {p4.x, p4.y, p4.z, p4.w};
    const float theta = exp2f(-(float)kk * 0.8304820237218406f);
    const long base = (((long)(bb * 16 + h)) * 2048 + s) * 128 + kk * 8;
    short8 q8 = *(short8*)(Qh + base);
    short8 k8 = *(short8*)(Kh + base);
    short8 qo, ko;
#pragma unroll
    for (int jj = 0; jj < 4; ++jj) {
      const float fr = pv[jj] * theta;
      float sn, c;
      __sincosf(fr, &sn, &c);
      {
        const float tr = b2f(q8[2 * jj]), ti = b2f(q8[2 * jj + 1]);
        qo[2 * jj] = f2b(tr * c - ti * sn);
        qo[2 * jj + 1] = f2b(tr * sn + ti * c);
      }
      {
        const float tr = b2f(k8[2 * jj]), ti = b2f(k8[2 * jj + 1]);
        ko[2 * jj] = f2b(tr * c - ti * sn);
        ko[2 * jj + 1] = f2b(tr * sn + ti * c);
      }
    }
    *(short8*)(Qh + base) = qo;
    *(short8*)(Kh + base) = ko;
  } else {
    // ---- V transpose: vlin [token][h*128+hd] -> Vt [b][h][hd][s] ----
    const int b2 = bx - 4096;  // 0..2047
    const int s0 = (b2 & 31) * 64;
    const int hd0 = ((b2 >> 5) & 1) * 64;
    const int bh = b2 >> 6;
    const int bb = bh >> 4, h = bh & 15;
    const int t = threadIdx.x;
#pragma unroll
    for (int i = 0; i < 2; ++i) {
      const int ch = t + i * 256;
      const int r = ch >> 3, c = ch & 7;
      *(short8*)&tile[r * 72 + c * 8] =
          *(const short8*)(v_lin + (long)(bb * 2048 + s0 + r) * 2048 + h * 128 + hd0 + c * 8);
    }
    __syncthreads();
#pragma unroll
    for (int i = 0; i < 2; ++i) {
      const int ch = t + i * 256;
      const int r2 = ch >> 3, c2 = ch & 7;
      short8 o;
#pragma unroll
      for (int u = 0; u < 8; ++u) o[u] = tile[(c2 * 8 + u) * 72 + r2];
      *(short8*)(Vt + ((long)(bh * 128 + hd0 + r2)) * 2048 + s0 + c2 * 8) = o;
    }
  }
}

// ---------------- flash attention v7: R6 proven body + LPT dispatch (R8 best) ----------
// R8 result: flash < 124us (out of top-5), no spill, LPT removed the tail. UNCHANGED.
__global__ __launch_bounds__(256, 3) void flash(const short* __restrict__ Qh,
                                                const short* __restrict__ Kh,
                                                const short* __restrict__ Vt,
                                                short* __restrict__ ao) {
  __shared__ short Ks[64 * 128];    // 16384 B: row=k (64), 16 chunks of 8sh; phys chunk = (c&8)|((c&7)^(row&7))
  __shared__ short Vts[128 * 64];   // 16384 B: row=hd (128), 8 chunks; phys chunk = c^(row&7)
  __shared__ short Ps[4 * 16 * 64]; // 8192 B: per-wave [16][64], 8 chunks; phys chunk = c^(row&7)
  const int id = blockIdx.x;        // 0..1023
  const int qt = 31 - (id >> 5);    // LPT: heaviest (qt=31) first
  const int bh = id & 31;
  const int t = threadIdx.x, wave = t >> 6, lane = t & 63, l15 = lane & 15, quad = lane >> 4;
  const int sqb = qt * 64;
  const int lastkt = qt;

  const short* Qbase = Qh + (long)bh * 2048 * 128;
  short8 aq[4];
#pragma unroll
  for (int ks = 0; ks < 4; ++ks)
    aq[ks] = *(const short8*)(Qbase + (long)(sqb + wave * 16 + l15) * 128 + ks * 32 + quad * 8);

  const short* KgBase = Kh + (long)bh * 2048 * 128;
  const short* VgBase = Vt + (long)bh * 128 * 2048;

  short8 kreg[4], vreg[4];
#pragma unroll
  for (int i = 0; i < 4; ++i) {
    const int ch = t + i * 256;
    kreg[i] = *(const short8*)(KgBase + (long)(ch >> 4) * 128 + (ch & 15) * 8);
    vreg[i] = *(const short8*)(VgBase + (long)(ch >> 3) * 2048 + (ch & 7) * 8);
  }

  float l_part[4] = {};
  floatx4 acc_o[8] = {};
  const float CEXP = 0.12751745f;  // (1/sqrt(128)) * log2(e)

  for (int kt = 0; kt <= lastkt; ++kt) {
    const int k0 = kt * 64;
    if (kt > 0) __syncthreads();

    // ---- stage K/V tile kt into swizzled LDS ----
#pragma unroll
    for (int i = 0; i < 4; ++i) {
      const int ch = t + i * 256;
      const int kr = ch >> 4, kc = ch & 15;
      *(short8*)&Ks[kr * 128 + (((kc & 7) ^ (kr & 7)) | (kc & 8)) * 8] = kreg[i];
      const int vr = ch >> 3, vc = ch & 7;
      *(short8*)&Vts[vr * 64 + (vc ^ (vr & 7)) * 8] = vreg[i];
    }
    __syncthreads();

    if (kt < lastkt) {
      const short* Kg = KgBase + (long)(k0 + 64) * 128;
      const short* Vg = VgBase + (k0 + 64);
#pragma unroll
      for (int i = 0; i < 4; ++i) {
        const int ch = t + i * 256;
        kreg[i] = *(const short8*)(Kg + (long)(ch >> 4) * 128 + (ch & 15) * 8);
        vreg[i] = *(const short8*)(Vg + (long)(ch >> 3) * 2048 + (ch & 7) * 8);
      }
    }

    const bool dg = (kt == lastkt);
    floatx4 accs[4] = {};
    __builtin_amdgcn_s_setprio(1);
#pragma unroll
    for (int ks = 0; ks < 4; ++ks) {
#pragma unroll
      for (int ni = 0; ni < 4; ++ni) {
        const int rr = ni * 16 + l15;
        const int c = ks * 4 + quad;  // logical chunk 0..15
        const short8 bk = *(const short8*)&Ks[rr * 128 + (((c & 7) ^ (rr & 7)) | (c & 8)) * 8];
        accs[ni] = __builtin_amdgcn_mfma_f32_16x16x32_bf16(aq[ks], bk, accs[ni], 0, 0, 0);
      }
    }
    __builtin_amdgcn_s_setprio(0);
#pragma unroll
    for (int r = 0; r < 4; ++r) {
      const int qrow = sqb + wave * 16 + quad * 4 + r;
      const int prow = quad * 4 + r;
#pragma unroll
      for (int ni = 0; ni < 4; ++ni) {
        float e = exp2f(accs[ni][r] * CEXP);
        if (dg && (k0 + ni * 16 + l15) > qrow) e = 0.f;
        const int pc = ni * 2 + (l15 >> 3);  // logical chunk 0..7
        Ps[wave * 1024 + prow * 64 + (pc ^ (prow & 7)) * 8 + (l15 & 7)] = f2b(e);
        l_part[r] += e;
      }
    }
    __builtin_amdgcn_s_setprio(1);
#pragma unroll
    for (int ks2 = 0; ks2 < 2; ++ks2) {
      const int pc = ks2 * 4 + quad;  // logical chunk 0..7
      const short8 ap = *(const short8*)&Ps[wave * 1024 + l15 * 64 + (pc ^ (l15 & 7)) * 8];
#pragma unroll
      for (int nh = 0; nh < 8; ++nh) {
        const int vr = nh * 16 + l15;
        const short8 bv = *(const short8*)&Vts[vr * 64 + (pc ^ (vr & 7)) * 8];
        acc_o[nh] = __builtin_amdgcn_mfma_f32_16x16x32_bf16(ap, bv, acc_o[nh], 0, 0, 0);
      }
    }
    __builtin_amdgcn_s_setprio(0);
  }

  const int bb = bh >> 4, h = bh & 15;
#pragma unroll
  for (int r = 0; r < 4; ++r) {
    float rs = l_part[r];
#pragma unroll
    for (int mm = 8; mm >= 1; mm >>= 1) rs += __shfl_xor(rs, mm, 16);
    const float inv = 1.0f / rs;
    const int s = sqb + wave * 16 + quad * 4 + r;
    const long rowbase = ((long)(bb * 2048 + s)) * 2048 + h * 128;
#pragma unroll
    for (int nh = 0; nh < 8; ++nh) ao[rowbase + nh * 16 + l15] = f2b(acc_o[nh][r] * inv);
  }
}

extern "C" void kernel_launch(void* const* d_in, const int* in_sizes, int n_in,
                              void* d_out, int out_size, void* d_ws, size_t ws_size,
                              hipStream_t stream) {
  const float* x = (const float*)d_in[0];
  const float* pos = (const float*)d_in[1];
  const float* wq = (const float*)d_in[3];
  const float* wk = (const float*)d_in[4];
  const float* wv = (const float*)d_in[5];
  const float* wo = (const float*)d_in[6];
  float* out = (float*)d_out;

  char* ws = (char*)d_ws;
  const size_t MB = 1024 * 1024;
  short* xb    = (short*)(ws + 0);        // 16 MB
  short* wqkvb = (short*)(ws + 16 * MB);  // 24 MB
  short* wob   = (short*)(ws + 40 * MB);  // 8 MB
  short* Qh    = (short*)(ws + 48 * MB);  // 16 MB
  short* Kh    = (short*)(ws + 64 * MB);  // 16 MB
  short* Vt    = (short*)(ws + 80 * MB);  // 16 MB
  short* vlin  = (short*)(ws + 96 * MB);  // 16 MB
  short* ao    = (short*)(ws + 96 * MB);  // alias vlin (vtrans consumes vlin before flash)
  // total 112 MB

  cast_all<<<24576, 256, 0, stream>>>(x, wq, wk, wv, wo, xb);

  qkv_gemm<<<dim3(48, 16), 512, 0, stream>>>(xb, wqkvb, Qh, Kh, vlin);

  rope_vtrans<<<6144, 256, 0, stream>>>(Qh, Kh, pos, vlin, Vt);

  flash<<<1024, 256, 0, stream>>>(Qh, Kh, Vt, ao);

  gemm_out<<<dim3(16, 32), 256, 0, stream>>>(ao, wob, out);
}